// Round 6
// baseline (192.563 us; speedup 1.0000x reference)
//
#include <hip/hip_runtime.h>
#include <math.h>
#include <stdint.h>

// RelPositionMultiheadAttention (Transformer-XL style).
// L=2048, N=4, E=256, H=4, D=64.
//   1) qkvpos_gemm: fused qkv-proj + pos-proj (fp16 MFMA) -> qu/qv/K [bh][i][d],
//      V^T [bh][d][j], P [h][n][d]   (unchanged, verified round 5)
//   2) attn_mfma: fused flash attention on 32x32x16 MFMA (this round's rewrite)
//   3) out_gemm: out = attn @ out_proj_w.T + b  (unchanged, verified round 5)

typedef __attribute__((ext_vector_type(8))) _Float16 half8;
typedef __attribute__((ext_vector_type(4))) float f32x4;
typedef __attribute__((ext_vector_type(16))) float f32x16;
typedef unsigned short u16;
typedef unsigned int u32;

namespace {
constexpr int L_SEQ  = 2048;
constexpr int NB     = 4;
constexpr int EMB    = 256;
constexpr int NH     = 4;
constexpr int HD     = 64;
constexpr int P_ROWS = 2 * L_SEQ - 1;  // 4095
}

__device__ __forceinline__ u16 f2h(float x) {
    _Float16 h = (_Float16)x;
    return __builtin_bit_cast(u16, h);
}
__device__ __forceinline__ u32 pk2(float a, float b) {
    return (u32)f2h(a) | ((u32)f2h(b) << 16);
}

// ---------------------------------------------------------------------------
// Fused qkv + pos projection (UNCHANGED from round 5, verified).
// ---------------------------------------------------------------------------
__global__ __launch_bounds__(256, 2) void qkvpos_gemm(
        const float* __restrict__ x, const float* __restrict__ pos_emb,
        const float* __restrict__ in_w, const float* __restrict__ in_b,
        const float* __restrict__ pos_w,
        const float* __restrict__ u_bias, const float* __restrict__ v_bias,
        u16* __restrict__ quB, u16* __restrict__ qvB,
        u16* __restrict__ kB,  u16* __restrict__ vtB, u16* __restrict__ pB) {
    __shared__ __align__(16) u16 ws[64 * 256];   // 32 KB swizzled W [n][k]
    __shared__ __align__(16) u16 scr[128 * 72];  // 18 KB epilogue scratch

    const int t    = threadIdx.x;
    const int lane = t & 63;
    const int w    = t >> 6;
    const int il   = lane & 15;
    const int g    = lane >> 4;

    const int logical = (blockIdx.x & 7) * 112 + (blockIdx.x >> 3);
    const bool isQKV = logical < 768;
    int mg, nt;
    const float *Ap, *W, *Wb;
    if (isQKV) { mg = logical / 12; nt = logical % 12; Ap = x;       W = in_w;  Wb = in_b; }
    else       { const int l2 = logical - 768;
                 mg = l2 >> 2;     nt = l2 & 3;      Ap = pos_emb; W = pos_w; Wb = nullptr; }
    const int m0 = mg * 128, n0 = nt * 64;

    {
        const int kc = (t & 31) * 8, rb_ = t >> 5;
        #pragma unroll
        for (int rr = 0; rr < 8; ++rr) {
            const int row = rb_ * 8 + rr;
            const float* wr = &W[(size_t)(n0 + row) * 256 + kc];
            float4 f0 = *(const float4*)&wr[0];
            float4 f1 = *(const float4*)&wr[4];
            *(uint4*)((char*)ws + row * 512 + ((kc * 2) ^ ((row & 7) << 4))) =
                make_uint4(pk2(f0.x, f0.y), pk2(f0.z, f0.w),
                           pk2(f1.x, f1.y), pk2(f1.z, f1.w));
        }
    }

    half8 bf0[8], bf1[8];
    {
        int r0 = m0 + w * 32 + il;
        int r1 = r0 + 16;
        if (!isQKV) { r0 = r0 > 4094 ? 4094 : r0; r1 = r1 > 4094 ? 4094 : r1; }
        const float* a0 = Ap + (size_t)r0 * 256;
        const float* a1 = Ap + (size_t)r1 * 256;
        #pragma unroll
        for (int c = 0; c < 8; ++c) {
            float4 f0 = *(const float4*)&a0[c * 32 + g * 8];
            float4 f1 = *(const float4*)&a0[c * 32 + g * 8 + 4];
            bf0[c] = __builtin_bit_cast(half8,
                make_uint4(pk2(f0.x, f0.y), pk2(f0.z, f0.w),
                           pk2(f1.x, f1.y), pk2(f1.z, f1.w)));
            float4 h0 = *(const float4*)&a1[c * 32 + g * 8];
            float4 h1 = *(const float4*)&a1[c * 32 + g * 8 + 4];
            bf1[c] = __builtin_bit_cast(half8,
                make_uint4(pk2(h0.x, h0.y), pk2(h0.z, h0.w),
                           pk2(h1.x, h1.y), pk2(h1.z, h1.w)));
        }
    }
    __syncthreads();

    f32x4 acc0[4] = {}, acc1[4] = {};
    __builtin_amdgcn_s_setprio(1);
    #pragma unroll
    for (int c = 0; c < 8; ++c) {
        #pragma unroll
        for (int jt = 0; jt < 4; ++jt) {
            const int row = jt * 16 + il;
            half8 af = *(const half8*)((const char*)ws + row * 512 +
                                       ((c * 64 + g * 16) ^ ((row & 7) << 4)));
            acc0[jt] = __builtin_amdgcn_mfma_f32_16x16x32_f16(af, bf0[c], acc0[jt], 0, 0, 0);
            acc1[jt] = __builtin_amdgcn_mfma_f32_16x16x32_f16(af, bf1[c], acc1[jt], 0, 0, 0);
        }
    }
    __builtin_amdgcn_s_setprio(0);

    float av[2][4][4];
    #pragma unroll
    for (int jt = 0; jt < 4; ++jt)
        #pragma unroll
        for (int r = 0; r < 4; ++r) {
            const float bb = Wb ? Wb[n0 + jt * 16 + g * 4 + r] : 0.f;
            av[0][jt][r] = acc0[jt][r] + bb;
            av[1][jt][r] = acc1[jt][r] + bb;
        }

    u16* scrw = scr + w * (32 * 72);
    const int rrd  = lane >> 1;
    const int base = (lane & 1) * 32;

    auto waveStore = [&](u16* dstBase, int hh, float scale, const float* bias,
                         bool qkvLayout) {
        #pragma unroll
        for (int s = 0; s < 2; ++s)
            #pragma unroll
            for (int jt = 0; jt < 4; ++jt) {
                const int d0 = jt * 16 + g * 4;
                float v0 = av[s][jt][0] * scale, v1 = av[s][jt][1] * scale;
                float v2 = av[s][jt][2] * scale, v3 = av[s][jt][3] * scale;
                if (bias) {
                    v0 += bias[hh * 64 + d0 + 0]; v1 += bias[hh * 64 + d0 + 1];
                    v2 += bias[hh * 64 + d0 + 2]; v3 += bias[hh * 64 + d0 + 3];
                }
                *(uint2*)&scrw[(s * 16 + il) * 72 + d0] = make_uint2(pk2(v0, v1), pk2(v2, v3));
            }
        uint4 q0 = *(const uint4*)&scrw[rrd * 72 + base + 0];
        uint4 q1 = *(const uint4*)&scrw[rrd * 72 + base + 8];
        uint4 q2 = *(const uint4*)&scrw[rrd * 72 + base + 16];
        uint4 q3 = *(const uint4*)&scrw[rrd * 72 + base + 24];
        const int mglob = m0 + w * 32 + rrd;
        if (qkvLayout) {
            const int i = mglob >> 2, b = mglob & 3;
            u16* dp = dstBase + (((size_t)(b * 4 + hh)) * 2048 + i) * 64 + base;
            *(uint4*)&dp[0] = q0; *(uint4*)&dp[8] = q1;
            *(uint4*)&dp[16] = q2; *(uint4*)&dp[24] = q3;
        } else if (mglob < P_ROWS) {
            u16* dp = dstBase + ((size_t)hh * P_ROWS + mglob) * 64 + base;
            *(uint4*)&dp[0] = q0; *(uint4*)&dp[8] = q1;
            *(uint4*)&dp[16] = q2; *(uint4*)&dp[24] = q3;
        }
    };

    if (isQKV) {
        const int seg = nt >> 2, h = nt & 3;
        if (seg == 0) {
            waveStore(quB, h, 0.125f, u_bias, true);
            waveStore(qvB, h, 0.125f, v_bias, true);
        } else if (seg == 1) {
            waveStore(kB, h, 1.f, nullptr, true);
        } else {
            #pragma unroll
            for (int s = 0; s < 2; ++s)
                #pragma unroll
                for (int jt = 0; jt < 4; ++jt)
                    *(uint2*)&scr[(w * 32 + s * 16 + il) * 72 + jt * 16 + g * 4] =
                        make_uint2(pk2(av[s][jt][0], av[s][jt][1]),
                                   pk2(av[s][jt][2], av[s][jt][3]));
            __syncthreads();
            const int b_ = w, d = lane;
            u32 pkx[16];
            #pragma unroll
            for (int z = 0; z < 16; ++z)
                pkx[z] = (u32)scr[((2 * z) * 4 + b_) * 72 + d] |
                         ((u32)scr[((2 * z + 1) * 4 + b_) * 72 + d] << 16);
            u16* dp = vtB + (((size_t)(b_ * 4 + h)) * 64 + d) * 2048 + mg * 32;
            *(uint4*)&dp[0]  = make_uint4(pkx[0],  pkx[1],  pkx[2],  pkx[3]);
            *(uint4*)&dp[8]  = make_uint4(pkx[4],  pkx[5],  pkx[6],  pkx[7]);
            *(uint4*)&dp[16] = make_uint4(pkx[8],  pkx[9],  pkx[10], pkx[11]);
            *(uint4*)&dp[24] = make_uint4(pkx[12], pkx[13], pkx[14], pkx[15]);
        }
    } else {
        waveStore(pB, nt, 1.f, nullptr, false);
    }
}

// ---------------------------------------------------------------------------
// out = attn @ out_proj_w.T + b (UNCHANGED from round 5, verified).
// ---------------------------------------------------------------------------
__global__ __launch_bounds__(256, 2) void out_gemm(
        const u16* __restrict__ attnb, const float* __restrict__ W,
        const float* __restrict__ Wb, float* __restrict__ outf) {
    __shared__ __align__(16) u16 ws[64 * 256];

    const int t    = threadIdx.x;
    const int lane = t & 63;
    const int w    = t >> 6;
    const int il   = lane & 15;
    const int g    = lane >> 4;

    const int logical = (blockIdx.x & 7) * 32 + (blockIdx.x >> 3);
    const int mg = logical >> 2, nt = logical & 3;
    const int m0 = mg * 128, n0 = nt * 64;

    {
        const int kc = (t & 31) * 8, rb_ = t >> 5;
        #pragma unroll
        for (int rr = 0; rr < 8; ++rr) {
            const int row = rb_ * 8 + rr;
            const float* wr = &W[(size_t)(n0 + row) * 256 + kc];
            float4 f0 = *(const float4*)&wr[0];
            float4 f1 = *(const float4*)&wr[4];
            *(uint4*)((char*)ws + row * 512 + ((kc * 2) ^ ((row & 7) << 4))) =
                make_uint4(pk2(f0.x, f0.y), pk2(f0.z, f0.w),
                           pk2(f1.x, f1.y), pk2(f1.z, f1.w));
        }
    }
    half8 bf0[8], bf1[8];
    {
        const u16* a0 = attnb + (size_t)(m0 + w * 32 + il) * 256;
        const u16* a1 = a0 + 16 * 256;
        #pragma unroll
        for (int c = 0; c < 8; ++c) {
            bf0[c] = *(const half8*)&a0[c * 32 + g * 8];
            bf1[c] = *(const half8*)&a1[c * 32 + g * 8];
        }
    }
    __syncthreads();

    f32x4 acc0[4] = {}, acc1[4] = {};
    __builtin_amdgcn_s_setprio(1);
    #pragma unroll
    for (int c = 0; c < 8; ++c) {
        #pragma unroll
        for (int jt = 0; jt < 4; ++jt) {
            const int row = jt * 16 + il;
            half8 af = *(const half8*)((const char*)ws + row * 512 +
                                       ((c * 64 + g * 16) ^ ((row & 7) << 4)));
            acc0[jt] = __builtin_amdgcn_mfma_f32_16x16x32_f16(af, bf0[c], acc0[jt], 0, 0, 0);
            acc1[jt] = __builtin_amdgcn_mfma_f32_16x16x32_f16(af, bf1[c], acc1[jt], 0, 0, 0);
        }
    }
    __builtin_amdgcn_s_setprio(0);

    #pragma unroll
    for (int s = 0; s < 2; ++s) {
        const int m_ = m0 + w * 32 + s * 16 + il;
        float* orow = &outf[(size_t)m_ * 256 + n0];
        #pragma unroll
        for (int jt = 0; jt < 4; ++jt) {
            const f32x4 a = s ? acc1[jt] : acc0[jt];
            *(float4*)&orow[jt * 16 + g * 4] = make_float4(
                a[0] + Wb[n0 + jt * 16 + g * 4 + 0],
                a[1] + Wb[n0 + jt * 16 + g * 4 + 1],
                a[2] + Wb[n0 + jt * 16 + g * 4 + 2],
                a[3] + Wb[n0 + jt * 16 + g * 4 + 3]);
        }
    }
}

// ---------------------------------------------------------------------------
// Fused rel-pos flash attention, 32x32x16 fp16 MFMA (rewrite).
// grid 512 (XCD-swizzled -> (bh, i0)), block 128 = 2 waves, 64 q-rows/block,
// wave owns 32 q (col = lane&31).  Per 64-j tile:
//   BD^T band: 3x 32-row tiles -> per-wave bd_s[96][34] f32 (conflict-free)
//   S^T = mfma(K, Qu) + diagonal gather from bd_s (32x ds_read_b32, imm offs)
//   online softmax (2 lanes/q -> single shfl_xor(32))
//   PV: P via per-wave [q][j] prob buffer (pitch 20 words, aligned b128 reads)
// C/D map (m74/m101): col=lane&31, row=(reg&3)+8*(reg>>2)+4*(lane>>5).
// LDS: 8+8+16+25.5+5 = 62.5 KB, 2 blocks/CU.
// ---------------------------------------------------------------------------
__global__ __launch_bounds__(128, 1) void attn_mfma(
        const u16* __restrict__ quB, const u16* __restrict__ qvB,
        const u16* __restrict__ kB,  const u16* __restrict__ vtB,
        const u16* __restrict__ pB,  u16* __restrict__ attn_out) {
    __shared__ __align__(16) u16   k_s[64 * 64];        // [j][d]   8 KB
    __shared__ __align__(16) u16   v_s[64 * 64];        // [d][j]   8 KB
    __shared__ __align__(16) u16   p_s[128 * 64];       // [r][d]  16 KB
    __shared__ __align__(16) float bd_f[2 * 96 * 34];   // per-wave band, 25.5 KB
    __shared__ __align__(16) u32   pb_u[2 * 32 * 20];   // per-wave [q][j] probs, 5 KB

    const int t    = threadIdx.x;
    const int lane = t & 63;
    const int w    = t >> 6;            // 0..1
    const int l31  = lane & 31;         // q within wave
    const int hi   = lane >> 5;         // k-half / row-half
    const int hi4  = hi * 4;

    const int logical = ((blockIdx.x & 7) << 6) + (blockIdx.x >> 3);
    const int bh = logical >> 5;        // 0..15
    const int i0 = (logical & 31) * 64;
    const int b  = bh >> 2, h = bh & 3;

    // A-frag column offsets (swizzled), row&7 == l31&7 for all our row bases
    int cx[4];
    {
        const int swz = (l31 & 7) << 4;
        #pragma unroll
        for (int ks = 0; ks < 4; ++ks)
            cx[ks] = ((ks * 32 + hi * 16) ^ swz);
    }
    const int rowb = l31 * 128;         // byte offset of row l31

    // B-fragments: Qu/Qv for q-row (i0 + w*32 + l31), k-slice ks*16 + hi*8
    half8 qu_f[4], qv_f[4];
    {
        const size_t qrow = ((size_t)bh * L_SEQ + i0 + w * 32 + l31) * HD + hi * 8;
        #pragma unroll
        for (int ks = 0; ks < 4; ++ks) {
            qu_f[ks] = *(const half8*)&quB[qrow + ks * 16];
            qv_f[ks] = *(const half8*)&qvB[qrow + ks * 16];
        }
    }

    // bd_s bases (floats): write W0, gather G0
    const int W0 = w * 3264 + hi4 * 34 + l31;
    const int G0 = w * 3264 + (31 - l31 + hi4) * 34 + l31;
    // prob bases (u32 words / bytes)
    const int PW = w * 640 + l31 * 20;          // word base for writes
    const int PRB = (w * 640 + l31 * 20) * 4 + hi * 16;  // byte base for b128 reads

    // staging
    const int rw = t >> 3, a8 = t & 7;
    const int wcol = (a8 * 16) ^ ((rw & 7) << 4);
    const int R0 = 32 - 32 * w;
    const int nb0 = 1984 - i0;

    f32x16 out0 = {}, out1 = {};
    float m_run = -INFINITY, l_run = 0.f;

    for (int kt = 0; kt < 32; ++kt) {
        const int j0 = kt * 64;
        const int nb = nb0 + j0;
        __syncthreads();
        // ---- stage K, V^T, P (fp16, swizzled) ----
        #pragma unroll
        for (int kr = 0; kr < 4; ++kr) {
            const int j = kr * 16 + rw;
            uint4 val = *(const uint4*)&kB[((size_t)bh * 2048 + j0 + j) * 64 + a8 * 8];
            *(uint4*)((char*)k_s + j * 128 + wcol) = val;
        }
        #pragma unroll
        for (int vr = 0; vr < 4; ++vr) {
            const int d = vr * 16 + rw;
            uint4 val = *(const uint4*)&vtB[((size_t)bh * 64 + d) * 2048 + j0 + a8 * 8];
            *(uint4*)((char*)v_s + d * 128 + wcol) = val;
        }
        #pragma unroll
        for (int pr = 0; pr < 8; ++pr) {
            const int r = pr * 16 + rw;
            int n = nb + r; n = n > (P_ROWS - 1) ? (P_ROWS - 1) : n; n = n < 0 ? 0 : n;
            uint4 val = *(const uint4*)&pB[((size_t)h * P_ROWS + n) * 64 + a8 * 8];
            *(uint4*)((char*)p_s + r * 128 + wcol) = val;
        }
        __syncthreads();

        // ---- BD^T band: 3 tiles of 32 rows ----
        __builtin_amdgcn_s_setprio(1);
        #pragma unroll
        for (int rt = 0; rt < 3; ++rt) {
            f32x16 bda = {};
            #pragma unroll
            for (int ks = 0; ks < 4; ++ks) {
                half8 a = *(const half8*)((const char*)p_s + (R0 + rt * 32) * 128 + rowb + cx[ks]);
                bda = __builtin_amdgcn_mfma_f32_32x32x16_f16(a, qv_f[ks], bda, 0, 0, 0);
            }
            #pragma unroll
            for (int r = 0; r < 16; ++r)
                bd_f[W0 + (rt * 32 + (r & 3) + 8 * (r >> 2)) * 34] = bda[r];
        }

        // ---- AC: S^T tiles (j 0..31, 32..63) ----
        f32x16 s0 = {}, s1 = {};
        #pragma unroll
        for (int ks = 0; ks < 4; ++ks) {
            half8 a0 = *(const half8*)((const char*)k_s + rowb + cx[ks]);
            s0 = __builtin_amdgcn_mfma_f32_32x32x16_f16(a0, qu_f[ks], s0, 0, 0, 0);
        }
        #pragma unroll
        for (int ks = 0; ks < 4; ++ks) {
            half8 a1 = *(const half8*)((const char*)k_s + 32 * 128 + rowb + cx[ks]);
            s1 = __builtin_amdgcn_mfma_f32_32x32x16_f16(a1, qu_f[ks], s1, 0, 0, 0);
        }
        __builtin_amdgcn_s_setprio(0);

        // ---- rel-shift combine: diagonal gather ----
        #pragma unroll
        for (int r = 0; r < 16; ++r) {
            const int off = ((r & 3) + 8 * (r >> 2)) * 34;
            s0[r] += bd_f[G0 + off];
            s1[r] += bd_f[G0 + 1088 + off];
        }

        // ---- online softmax (cols lane&31; partner lane^32) ----
        float mx = s0[0];
        #pragma unroll
        for (int r = 1; r < 16; ++r) mx = fmaxf(mx, s0[r]);
        #pragma unroll
        for (int r = 0; r < 16; ++r) mx = fmaxf(mx, s1[r]);
        mx = fmaxf(mx, __shfl_xor(mx, 32));
        const float m_new = fmaxf(m_run, mx);
        const float corr = __expf(m_run - m_new);
        float lsum = 0.f;
        #pragma unroll
        for (int r = 0; r < 16; ++r) { s0[r] = __expf(s0[r] - m_new); lsum += s0[r]; }
        #pragma unroll
        for (int r = 0; r < 16; ++r) { s1[r] = __expf(s1[r] - m_new); lsum += s1[r]; }
        lsum += __shfl_xor(lsum, 32);
        l_run = l_run * corr + lsum;
        m_run = m_new;
        #pragma unroll
        for (int r = 0; r < 16; ++r) { out0[r] *= corr; out1[r] *= corr; }

        // ---- PV per j-tile: prob buffer round-trip + 32x32 MFMAs ----
        #pragma unroll
        for (int jt = 0; jt < 2; ++jt) {
            #pragma unroll
            for (int k4 = 0; k4 < 4; ++k4) {
                const float e0 = jt ? s1[k4 * 4 + 0] : s0[k4 * 4 + 0];
                const float e1 = jt ? s1[k4 * 4 + 1] : s0[k4 * 4 + 1];
                const float e2 = jt ? s1[k4 * 4 + 2] : s0[k4 * 4 + 2];
                const float e3 = jt ? s1[k4 * 4 + 3] : s0[k4 * 4 + 3];
                *(uint2*)&pb_u[PW + k4 * 4 + hi * 2] = make_uint2(pk2(e0, e1), pk2(e2, e3));
            }
            half8 pf0 = *(const half8*)((const char*)pb_u + PRB);
            half8 pf1 = *(const half8*)((const char*)pb_u + PRB + 32);
            __builtin_amdgcn_s_setprio(1);
            {
                half8 va = *(const half8*)((const char*)v_s + rowb + cx[jt * 2 + 0]);
                out0 = __builtin_amdgcn_mfma_f32_32x32x16_f16(va, pf0, out0, 0, 0, 0);
                half8 vb = *(const half8*)((const char*)v_s + rowb + cx[jt * 2 + 1]);
                out0 = __builtin_amdgcn_mfma_f32_32x32x16_f16(vb, pf1, out0, 0, 0, 0);
                half8 vc = *(const half8*)((const char*)v_s + 32 * 128 + rowb + cx[jt * 2 + 0]);
                out1 = __builtin_amdgcn_mfma_f32_32x32x16_f16(vc, pf0, out1, 0, 0, 0);
                half8 vd = *(const half8*)((const char*)v_s + 32 * 128 + rowb + cx[jt * 2 + 1]);
                out1 = __builtin_amdgcn_mfma_f32_32x32x16_f16(vd, pf1, out1, 0, 0, 0);
            }
            __builtin_amdgcn_s_setprio(0);
        }
    }

    // ---- epilogue: fp16 [m][e] ----
    const float inv = 1.f / l_run;
    const int i = i0 + w * 32 + l31;
    const int m = i * NB + b;
    u16* orow = &attn_out[(size_t)m * EMB + h * HD];
    #pragma unroll
    for (int k4 = 0; k4 < 4; ++k4) {
        const int d0 = k4 * 8 + hi4;
        *(uint2*)&orow[d0] = make_uint2(
            pk2(out0[k4 * 4 + 0] * inv, out0[k4 * 4 + 1] * inv),
            pk2(out0[k4 * 4 + 2] * inv, out0[k4 * 4 + 3] * inv));
        *(uint2*)&orow[32 + d0] = make_uint2(
            pk2(out1[k4 * 4 + 0] * inv, out1[k4 * 4 + 1] * inv),
            pk2(out1[k4 * 4 + 2] * inv, out1[k4 * 4 + 3] * inv));
    }
}

// ---------------------------------------------------------------------------
extern "C" void kernel_launch(void* const* d_in, const int* in_sizes, int n_in,
                              void* d_out, int out_size, void* d_ws, size_t ws_size,
                              hipStream_t stream) {
    const float* x        = (const float*)d_in[0];
    const float* pos_emb  = (const float*)d_in[1];
    const float* in_w     = (const float*)d_in[2];
    const float* in_b     = (const float*)d_in[3];
    const float* pos_w    = (const float*)d_in[4];
    const float* u_bias   = (const float*)d_in[5];
    const float* v_bias   = (const float*)d_in[6];
    const float* out_w    = (const float*)d_in[7];
    const float* out_b    = (const float*)d_in[8];
    float* out = (float*)d_out;

    u16* quB   = (u16*)d_ws;
    u16* qvB   = quB + (size_t)16 * L_SEQ * HD;
    u16* kB    = qvB + (size_t)16 * L_SEQ * HD;
    u16* vtB   = kB  + (size_t)16 * L_SEQ * HD;
    u16* pB    = vtB + (size_t)16 * L_SEQ * HD;
    u16* attnb = pB  + (size_t)NH * P_ROWS * HD;

    qkvpos_gemm<<<dim3(896), 256, 0, stream>>>(
        x, pos_emb, in_w, in_b, pos_w, u_bias, v_bias, quB, qvB, kB, vtB, pB);
    attn_mfma<<<dim3(512), 128, 0, stream>>>(quB, qvB, kB, vtB, pB, attnb);
    out_gemm<<<dim3(256), 256, 0, stream>>>(attnb, out_w, out_b, out);
}

// Round 7
// 176.348 us; speedup vs baseline: 1.0919x; 1.0919x over previous
//
#include <hip/hip_runtime.h>
#include <math.h>
#include <stdint.h>

// RelPositionMultiheadAttention (Transformer-XL style).
// L=2048, N=4, E=256, H=4, D=64.
//   1) qkvpos_gemm: fused qkv-proj + pos-proj (verified round 5, untouched)
//   2) attn_mfma: flash attention, 32x32x16 MFMA, q/j wave-split (this round)
//   3) out_gemm: out = attn @ out_proj_w.T + b (verified round 5, untouched)

typedef __attribute__((ext_vector_type(8))) _Float16 half8;
typedef __attribute__((ext_vector_type(4))) float f32x4;
typedef __attribute__((ext_vector_type(16))) float f32x16;
typedef unsigned short u16;
typedef unsigned int u32;

namespace {
constexpr int L_SEQ  = 2048;
constexpr int NB     = 4;
constexpr int EMB    = 256;
constexpr int NH     = 4;
constexpr int HD     = 64;
constexpr int P_ROWS = 2 * L_SEQ - 1;  // 4095
}

__device__ __forceinline__ u16 f2h(float x) {
    _Float16 h = (_Float16)x;
    return __builtin_bit_cast(u16, h);
}
__device__ __forceinline__ u32 pk2(float a, float b) {
    return (u32)f2h(a) | ((u32)f2h(b) << 16);
}

// ---------------------------------------------------------------------------
// Fused qkv + pos projection (UNCHANGED from round 5, verified).
// ---------------------------------------------------------------------------
__global__ __launch_bounds__(256, 2) void qkvpos_gemm(
        const float* __restrict__ x, const float* __restrict__ pos_emb,
        const float* __restrict__ in_w, const float* __restrict__ in_b,
        const float* __restrict__ pos_w,
        const float* __restrict__ u_bias, const float* __restrict__ v_bias,
        u16* __restrict__ quB, u16* __restrict__ qvB,
        u16* __restrict__ kB,  u16* __restrict__ vtB, u16* __restrict__ pB) {
    __shared__ __align__(16) u16 ws[64 * 256];   // 32 KB swizzled W [n][k]
    __shared__ __align__(16) u16 scr[128 * 72];  // 18 KB epilogue scratch

    const int t    = threadIdx.x;
    const int lane = t & 63;
    const int w    = t >> 6;
    const int il   = lane & 15;
    const int g    = lane >> 4;

    const int logical = (blockIdx.x & 7) * 112 + (blockIdx.x >> 3);
    const bool isQKV = logical < 768;
    int mg, nt;
    const float *Ap, *W, *Wb;
    if (isQKV) { mg = logical / 12; nt = logical % 12; Ap = x;       W = in_w;  Wb = in_b; }
    else       { const int l2 = logical - 768;
                 mg = l2 >> 2;     nt = l2 & 3;      Ap = pos_emb; W = pos_w; Wb = nullptr; }
    const int m0 = mg * 128, n0 = nt * 64;

    {
        const int kc = (t & 31) * 8, rb_ = t >> 5;
        #pragma unroll
        for (int rr = 0; rr < 8; ++rr) {
            const int row = rb_ * 8 + rr;
            const float* wr = &W[(size_t)(n0 + row) * 256 + kc];
            float4 f0 = *(const float4*)&wr[0];
            float4 f1 = *(const float4*)&wr[4];
            *(uint4*)((char*)ws + row * 512 + ((kc * 2) ^ ((row & 7) << 4))) =
                make_uint4(pk2(f0.x, f0.y), pk2(f0.z, f0.w),
                           pk2(f1.x, f1.y), pk2(f1.z, f1.w));
        }
    }

    half8 bf0[8], bf1[8];
    {
        int r0 = m0 + w * 32 + il;
        int r1 = r0 + 16;
        if (!isQKV) { r0 = r0 > 4094 ? 4094 : r0; r1 = r1 > 4094 ? 4094 : r1; }
        const float* a0 = Ap + (size_t)r0 * 256;
        const float* a1 = Ap + (size_t)r1 * 256;
        #pragma unroll
        for (int c = 0; c < 8; ++c) {
            float4 f0 = *(const float4*)&a0[c * 32 + g * 8];
            float4 f1 = *(const float4*)&a0[c * 32 + g * 8 + 4];
            bf0[c] = __builtin_bit_cast(half8,
                make_uint4(pk2(f0.x, f0.y), pk2(f0.z, f0.w),
                           pk2(f1.x, f1.y), pk2(f1.z, f1.w)));
            float4 h0 = *(const float4*)&a1[c * 32 + g * 8];
            float4 h1 = *(const float4*)&a1[c * 32 + g * 8 + 4];
            bf1[c] = __builtin_bit_cast(half8,
                make_uint4(pk2(h0.x, h0.y), pk2(h0.z, h0.w),
                           pk2(h1.x, h1.y), pk2(h1.z, h1.w)));
        }
    }
    __syncthreads();

    f32x4 acc0[4] = {}, acc1[4] = {};
    __builtin_amdgcn_s_setprio(1);
    #pragma unroll
    for (int c = 0; c < 8; ++c) {
        #pragma unroll
        for (int jt = 0; jt < 4; ++jt) {
            const int row = jt * 16 + il;
            half8 af = *(const half8*)((const char*)ws + row * 512 +
                                       ((c * 64 + g * 16) ^ ((row & 7) << 4)));
            acc0[jt] = __builtin_amdgcn_mfma_f32_16x16x32_f16(af, bf0[c], acc0[jt], 0, 0, 0);
            acc1[jt] = __builtin_amdgcn_mfma_f32_16x16x32_f16(af, bf1[c], acc1[jt], 0, 0, 0);
        }
    }
    __builtin_amdgcn_s_setprio(0);

    float av[2][4][4];
    #pragma unroll
    for (int jt = 0; jt < 4; ++jt)
        #pragma unroll
        for (int r = 0; r < 4; ++r) {
            const float bb = Wb ? Wb[n0 + jt * 16 + g * 4 + r] : 0.f;
            av[0][jt][r] = acc0[jt][r] + bb;
            av[1][jt][r] = acc1[jt][r] + bb;
        }

    u16* scrw = scr + w * (32 * 72);
    const int rrd  = lane >> 1;
    const int base = (lane & 1) * 32;

    auto waveStore = [&](u16* dstBase, int hh, float scale, const float* bias,
                         bool qkvLayout) {
        #pragma unroll
        for (int s = 0; s < 2; ++s)
            #pragma unroll
            for (int jt = 0; jt < 4; ++jt) {
                const int d0 = jt * 16 + g * 4;
                float v0 = av[s][jt][0] * scale, v1 = av[s][jt][1] * scale;
                float v2 = av[s][jt][2] * scale, v3 = av[s][jt][3] * scale;
                if (bias) {
                    v0 += bias[hh * 64 + d0 + 0]; v1 += bias[hh * 64 + d0 + 1];
                    v2 += bias[hh * 64 + d0 + 2]; v3 += bias[hh * 64 + d0 + 3];
                }
                *(uint2*)&scrw[(s * 16 + il) * 72 + d0] = make_uint2(pk2(v0, v1), pk2(v2, v3));
            }
        uint4 q0 = *(const uint4*)&scrw[rrd * 72 + base + 0];
        uint4 q1 = *(const uint4*)&scrw[rrd * 72 + base + 8];
        uint4 q2 = *(const uint4*)&scrw[rrd * 72 + base + 16];
        uint4 q3 = *(const uint4*)&scrw[rrd * 72 + base + 24];
        const int mglob = m0 + w * 32 + rrd;
        if (qkvLayout) {
            const int i = mglob >> 2, b = mglob & 3;
            u16* dp = dstBase + (((size_t)(b * 4 + hh)) * 2048 + i) * 64 + base;
            *(uint4*)&dp[0] = q0; *(uint4*)&dp[8] = q1;
            *(uint4*)&dp[16] = q2; *(uint4*)&dp[24] = q3;
        } else if (mglob < P_ROWS) {
            u16* dp = dstBase + ((size_t)hh * P_ROWS + mglob) * 64 + base;
            *(uint4*)&dp[0] = q0; *(uint4*)&dp[8] = q1;
            *(uint4*)&dp[16] = q2; *(uint4*)&dp[24] = q3;
        }
    };

    if (isQKV) {
        const int seg = nt >> 2, h = nt & 3;
        if (seg == 0) {
            waveStore(quB, h, 0.125f, u_bias, true);
            waveStore(qvB, h, 0.125f, v_bias, true);
        } else if (seg == 1) {
            waveStore(kB, h, 1.f, nullptr, true);
        } else {
            #pragma unroll
            for (int s = 0; s < 2; ++s)
                #pragma unroll
                for (int jt = 0; jt < 4; ++jt)
                    *(uint2*)&scr[(w * 32 + s * 16 + il) * 72 + jt * 16 + g * 4] =
                        make_uint2(pk2(av[s][jt][0], av[s][jt][1]),
                                   pk2(av[s][jt][2], av[s][jt][3]));
            __syncthreads();
            const int b_ = w, d = lane;
            u32 pkx[16];
            #pragma unroll
            for (int z = 0; z < 16; ++z)
                pkx[z] = (u32)scr[((2 * z) * 4 + b_) * 72 + d] |
                         ((u32)scr[((2 * z + 1) * 4 + b_) * 72 + d] << 16);
            u16* dp = vtB + (((size_t)(b_ * 4 + h)) * 64 + d) * 2048 + mg * 32;
            *(uint4*)&dp[0]  = make_uint4(pkx[0],  pkx[1],  pkx[2],  pkx[3]);
            *(uint4*)&dp[8]  = make_uint4(pkx[4],  pkx[5],  pkx[6],  pkx[7]);
            *(uint4*)&dp[16] = make_uint4(pkx[8],  pkx[9],  pkx[10], pkx[11]);
            *(uint4*)&dp[24] = make_uint4(pkx[12], pkx[13], pkx[14], pkx[15]);
        }
    } else {
        waveStore(pB, nt, 1.f, nullptr, false);
    }
}

// ---------------------------------------------------------------------------
// out = attn @ out_proj_w.T + b (UNCHANGED from round 5, verified).
// ---------------------------------------------------------------------------
__global__ __launch_bounds__(256, 2) void out_gemm(
        const u16* __restrict__ attnb, const float* __restrict__ W,
        const float* __restrict__ Wb, float* __restrict__ outf) {
    __shared__ __align__(16) u16 ws[64 * 256];

    const int t    = threadIdx.x;
    const int lane = t & 63;
    const int w    = t >> 6;
    const int il   = lane & 15;
    const int g    = lane >> 4;

    const int logical = (blockIdx.x & 7) * 32 + (blockIdx.x >> 3);
    const int mg = logical >> 2, nt = logical & 3;
    const int m0 = mg * 128, n0 = nt * 64;

    {
        const int kc = (t & 31) * 8, rb_ = t >> 5;
        #pragma unroll
        for (int rr = 0; rr < 8; ++rr) {
            const int row = rb_ * 8 + rr;
            const float* wr = &W[(size_t)(n0 + row) * 256 + kc];
            float4 f0 = *(const float4*)&wr[0];
            float4 f1 = *(const float4*)&wr[4];
            *(uint4*)((char*)ws + row * 512 + ((kc * 2) ^ ((row & 7) << 4))) =
                make_uint4(pk2(f0.x, f0.y), pk2(f0.z, f0.w),
                           pk2(f1.x, f1.y), pk2(f1.z, f1.w));
        }
    }
    half8 bf0[8], bf1[8];
    {
        const u16* a0 = attnb + (size_t)(m0 + w * 32 + il) * 256;
        const u16* a1 = a0 + 16 * 256;
        #pragma unroll
        for (int c = 0; c < 8; ++c) {
            bf0[c] = *(const half8*)&a0[c * 32 + g * 8];
            bf1[c] = *(const half8*)&a1[c * 32 + g * 8];
        }
    }
    __syncthreads();

    f32x4 acc0[4] = {}, acc1[4] = {};
    __builtin_amdgcn_s_setprio(1);
    #pragma unroll
    for (int c = 0; c < 8; ++c) {
        #pragma unroll
        for (int jt = 0; jt < 4; ++jt) {
            const int row = jt * 16 + il;
            half8 af = *(const half8*)((const char*)ws + row * 512 +
                                       ((c * 64 + g * 16) ^ ((row & 7) << 4)));
            acc0[jt] = __builtin_amdgcn_mfma_f32_16x16x32_f16(af, bf0[c], acc0[jt], 0, 0, 0);
            acc1[jt] = __builtin_amdgcn_mfma_f32_16x16x32_f16(af, bf1[c], acc1[jt], 0, 0, 0);
        }
    }
    __builtin_amdgcn_s_setprio(0);

    #pragma unroll
    for (int s = 0; s < 2; ++s) {
        const int m_ = m0 + w * 32 + s * 16 + il;
        float* orow = &outf[(size_t)m_ * 256 + n0];
        #pragma unroll
        for (int jt = 0; jt < 4; ++jt) {
            const f32x4 a = s ? acc1[jt] : acc0[jt];
            *(float4*)&orow[jt * 16 + g * 4] = make_float4(
                a[0] + Wb[n0 + jt * 16 + g * 4 + 0],
                a[1] + Wb[n0 + jt * 16 + g * 4 + 1],
                a[2] + Wb[n0 + jt * 16 + g * 4 + 2],
                a[3] + Wb[n0 + jt * 16 + g * 4 + 3]);
        }
    }
}

// ---------------------------------------------------------------------------
// Fused rel-pos flash attention v5: 32x32x16 MFMA, q/j wave-split.
// grid 512 (XCD-swizzled -> (bh, i0)), block 256 = 4 waves, 64 q-rows/block.
// Wave (qw = w&1, jw = w>>1) owns the 32q x 32j quadrant.
//   band: shared fp16 [64 Rpair][68 pitch]; wave computes r-tiles {2jw,2jw+1}
//         for its q-half (B = own qv). Gather = 16x ds_read_u16 (diagonal).
//   softmax: per-lane 16 j (own q col) -> xor32 -> cross-jw max via LDS;
//            l kept as own-half partial, merged post-loop with O partials.
//   PV: 32x32 tiles over own j-half; prob via per-wave [32q][20 u32] buffer.
// C/D map (m74/m101): col=lane&31, row=(reg&3)+8*(reg>>2)+4*(lane>>5).
// LDS = 8+8+16+17+10+0.75 KB = 59.8 KB -> 2 blocks/CU (2 waves/SIMD).
// ---------------------------------------------------------------------------
__global__ __launch_bounds__(256, 2) void attn_mfma(
        const u16* __restrict__ quB, const u16* __restrict__ qvB,
        const u16* __restrict__ kB,  const u16* __restrict__ vtB,
        const u16* __restrict__ pB,  u16* __restrict__ attn_out) {
    __shared__ __align__(16) u16 k_s[64 * 64];        // [j][d] swz   8 KB
    __shared__ __align__(16) u16 v_s[64 * 64];        // [d][j] swz   8 KB
    __shared__ __align__(16) u16 p_s[128 * 64];       // [r][d] swz  16 KB
    __shared__ __align__(16) u32 band_s[64 * 68];     // [Rpair][q] 17 KB
    __shared__ __align__(16) u32 prob_s[4][32 * 20];  // per-wave   10 KB
    __shared__ float mw_s[2][64];
    __shared__ float lb_s[64];

    const int t    = threadIdx.x;
    const int lane = t & 63;
    const int w    = t >> 6;
    const int qw   = w & 1;
    const int jw   = w >> 1;
    const int l31  = lane & 31;
    const int hi   = lane >> 5;

    const int logical = ((blockIdx.x & 7) << 6) + (blockIdx.x >> 3);
    const int bh = logical >> 5;
    const int i0 = (logical & 31) * 64;
    const int b  = bh >> 2, h = bh & 3;
    const int qloc = qw * 32 + l31;          // q within block

    // swizzled 128B-row column offsets (cx[c]: halfs c*16 + hi*8)
    int cx[4];
    {
        const int swz = (l31 & 7) << 4;
        #pragma unroll
        for (int c = 0; c < 4; ++c) cx[c] = ((c * 32 + hi * 16) ^ swz);
    }

    // B-fragments: own q-row (i0 + qloc), k-slice ks*16 + hi*8
    half8 qu_f[4], qv_f[4];
    {
        const size_t qrow = ((size_t)bh * L_SEQ + i0 + qloc) * HD + hi * 8;
        #pragma unroll
        for (int ks = 0; ks < 4; ++ks) {
            qu_f[ks] = *(const half8*)&quB[qrow + ks * 16];
            qv_f[ks] = *(const half8*)&qvB[qrow + ks * 16];
        }
    }

    // staging indices (r5-verified pattern)
    const int rw = t >> 3, a8 = t & 7;
    const int wcol = (a8 * 16) ^ ((rw & 7) << 4);
    const int nb0 = 1984 - i0;

    f32x16 o0 = {}, o1 = {};
    float m_run = -INFINITY, l_run = 0.f;

    for (int kt = 0; kt < 32; ++kt) {
        const int j0 = kt * 64;
        const int nb = nb0 + j0;
        __syncthreads();                                   // A
        // ---- stage K, V^T, P (fp16, swizzled) ----
        #pragma unroll
        for (int kr = 0; kr < 2; ++kr) {
            const int j = kr * 32 + rw;
            uint4 val = *(const uint4*)&kB[((size_t)bh * 2048 + j0 + j) * 64 + a8 * 8];
            *(uint4*)((char*)k_s + j * 128 + wcol) = val;
        }
        #pragma unroll
        for (int vr = 0; vr < 2; ++vr) {
            const int d = vr * 32 + rw;
            uint4 val = *(const uint4*)&vtB[((size_t)bh * 64 + d) * 2048 + j0 + a8 * 8];
            *(uint4*)((char*)v_s + d * 128 + wcol) = val;
        }
        #pragma unroll
        for (int pr = 0; pr < 4; ++pr) {
            const int r = pr * 32 + rw;
            int n = nb + r; n = n > (P_ROWS - 1) ? (P_ROWS - 1) : n; n = n < 0 ? 0 : n;
            uint4 val = *(const uint4*)&pB[((size_t)h * P_ROWS + n) * 64 + a8 * 8];
            *(uint4*)((char*)p_s + r * 128 + wcol) = val;
        }
        __syncthreads();                                   // B

        // ---- band: this wave computes r-tiles {2jw, 2jw+1} for its q-half ----
        __builtin_amdgcn_s_setprio(1);
        #pragma unroll
        for (int tti = 0; tti < 2; ++tti) {
            const int rt = 2 * jw + tti;
            f32x16 bda = {};
            #pragma unroll
            for (int ks = 0; ks < 4; ++ks) {
                half8 a = *(const half8*)((const char*)p_s + (rt * 32 + l31) * 128 + cx[ks]);
                bda = __builtin_amdgcn_mfma_f32_32x32x16_f16(a, qv_f[ks], bda, 0, 0, 0);
            }
            #pragma unroll
            for (int rr = 0; rr < 4; ++rr)
                #pragma unroll
                for (int p = 0; p < 2; ++p) {
                    const int Rp = rt * 16 + 4 * rr + 2 * hi + p;   // = R>>1 (R even)
                    band_s[Rp * 68 + qloc] = pk2(bda[rr * 4 + 2 * p], bda[rr * 4 + 2 * p + 1]);
                }
        }
        // ---- AC: own 32q x 32j quadrant ----
        f32x16 s = {};
        #pragma unroll
        for (int ks = 0; ks < 4; ++ks) {
            half8 a = *(const half8*)((const char*)k_s + (jw * 32 + l31) * 128 + cx[ks]);
            s = __builtin_amdgcn_mfma_f32_32x32x16_f16(a, qu_f[ks], s, 0, 0, 0);
        }
        __builtin_amdgcn_s_setprio(0);
        __syncthreads();                                   // C (band ready)

        // ---- rel-shift gather + combine ----
        float sr[16];
        #pragma unroll
        for (int r = 0; r < 16; ++r) {
            const int jrow = (r & 3) + 8 * (r >> 2) + 4 * hi;
            const int R = 63 - qloc + jw * 32 + jrow;
            _Float16 hv = ((const _Float16*)band_s)[(R >> 1) * 136 + qloc * 2 + (R & 1)];
            sr[r] = s[r] + (float)hv;
        }

        // ---- softmax: own-half max -> cross-jw exchange ----
        float mx = sr[0];
        #pragma unroll
        for (int r = 1; r < 16; ++r) mx = fmaxf(mx, sr[r]);
        mx = fmaxf(mx, __shfl_xor(mx, 32));
        mw_s[jw][qloc] = mx;
        __syncthreads();                                   // D
        const float m_tile = fmaxf(mx, mw_s[1 - jw][qloc]);
        const float m_new = fmaxf(m_run, m_tile);
        const float corr = __expf(m_run - m_new);
        float psum = 0.f;
        #pragma unroll
        for (int r = 0; r < 16; ++r) { sr[r] = __expf(sr[r] - m_new); psum += sr[r]; }
        psum += __shfl_xor(psum, 32);
        l_run = l_run * corr + psum;                       // own-half partial
        m_run = m_new;
        #pragma unroll
        for (int r = 0; r < 16; ++r) { o0[r] *= corr; o1[r] *= corr; }

        // ---- pack probs (own-wave buffer [q l31][j/2]) ----
        #pragma unroll
        for (int rr = 0; rr < 4; ++rr)
            #pragma unroll
            for (int p = 0; p < 2; ++p)
                prob_s[w][l31 * 20 + 4 * rr + 2 * hi + p] =
                    pk2(sr[rr * 4 + 2 * p], sr[rr * 4 + 2 * p + 1]);

        // ---- PV over own j-half ----
        half8 pf[2];
        #pragma unroll
        for (int ks2 = 0; ks2 < 2; ++ks2)
            pf[ks2] = *(const half8*)((const char*)&prob_s[w][0] +
                                      l31 * 80 + ks2 * 32 + hi * 16);
        __builtin_amdgcn_s_setprio(1);
        #pragma unroll
        for (int ks2 = 0; ks2 < 2; ++ks2) {
            half8 a0 = *(const half8*)((const char*)v_s + l31 * 128 + cx[2 * jw + ks2]);
            o0 = __builtin_amdgcn_mfma_f32_32x32x16_f16(a0, pf[ks2], o0, 0, 0, 0);
            half8 a1 = *(const half8*)((const char*)v_s + (32 + l31) * 128 + cx[2 * jw + ks2]);
            o1 = __builtin_amdgcn_mfma_f32_32x32x16_f16(a1, pf[ks2], o1, 0, 0, 0);
        }
        __builtin_amdgcn_s_setprio(0);
    }

    // ---- merge j-halves: jw=1 dumps partials, jw=0 combines + stores ----
    __syncthreads();
    float* ob = (float*)band_s;   // [64 q][65] f32 (16.6 KB <= band+)
    if (jw == 1) {
        #pragma unroll
        for (int r = 0; r < 16; ++r) {
            const int dr = 8 * (r >> 2) + 4 * hi + (r & 3);
            ob[qloc * 65 + dr] = o0[r];
            ob[qloc * 65 + 32 + dr] = o1[r];
        }
        lb_s[qloc] = l_run;
    }
    __syncthreads();
    if (jw == 0) {
        const float inv = 1.f / (l_run + lb_s[qloc]);
        const int m = (i0 + qloc) * NB + b;
        u16* orow = &attn_out[(size_t)m * EMB + h * HD];
        float of[32];
        #pragma unroll
        for (int r = 0; r < 16; ++r) {
            const int dr = 8 * (r >> 2) + 4 * hi + (r & 3);
            of[dr & 31] = 0.f;  // placeholder, overwritten below (keeps indices static)
        }
        #pragma unroll
        for (int r = 0; r < 16; ++r) {
            const int dr = 8 * (r >> 2) + 4 * hi + (r & 3);
            of[((r >> 2) * 8 + (r & 3)) & 31] = 0.f;  // no-op safety
            (void)dr;
        }
        #pragma unroll
        for (int rr = 0; rr < 4; ++rr) {
            const int d0 = rr * 8 + 4 * hi;
            float a0 = (o0[rr * 4 + 0] + ob[qloc * 65 + d0 + 0]) * inv;
            float a1 = (o0[rr * 4 + 1] + ob[qloc * 65 + d0 + 1]) * inv;
            float a2 = (o0[rr * 4 + 2] + ob[qloc * 65 + d0 + 2]) * inv;
            float a3 = (o0[rr * 4 + 3] + ob[qloc * 65 + d0 + 3]) * inv;
            *(uint2*)&orow[d0] = make_uint2(pk2(a0, a1), pk2(a2, a3));
            float b0 = (o1[rr * 4 + 0] + ob[qloc * 65 + 32 + d0 + 0]) * inv;
            float b1 = (o1[rr * 4 + 1] + ob[qloc * 65 + 32 + d0 + 1]) * inv;
            float b2 = (o1[rr * 4 + 2] + ob[qloc * 65 + 32 + d0 + 2]) * inv;
            float b3 = (o1[rr * 4 + 3] + ob[qloc * 65 + 32 + d0 + 3]) * inv;
            *(uint2*)&orow[32 + d0] = make_uint2(pk2(b0, b1), pk2(b2, b3));
        }
    }
}

// ---------------------------------------------------------------------------
extern "C" void kernel_launch(void* const* d_in, const int* in_sizes, int n_in,
                              void* d_out, int out_size, void* d_ws, size_t ws_size,
                              hipStream_t stream) {
    const float* x        = (const float*)d_in[0];
    const float* pos_emb  = (const float*)d_in[1];
    const float* in_w     = (const float*)d_in[2];
    const float* in_b     = (const float*)d_in[3];
    const float* pos_w    = (const float*)d_in[4];
    const float* u_bias   = (const float*)d_in[5];
    const float* v_bias   = (const float*)d_in[6];
    const float* out_w    = (const float*)d_in[7];
    const float* out_b    = (const float*)d_in[8];
    float* out = (float*)d_out;

    u16* quB   = (u16*)d_ws;
    u16* qvB   = quB + (size_t)16 * L_SEQ * HD;
    u16* kB    = qvB + (size_t)16 * L_SEQ * HD;
    u16* vtB   = kB  + (size_t)16 * L_SEQ * HD;
    u16* pB    = vtB + (size_t)16 * L_SEQ * HD;
    u16* attnb = pB  + (size_t)NH * P_ROWS * HD;

    qkvpos_gemm<<<dim3(896), 256, 0, stream>>>(
        x, pos_emb, in_w, in_b, pos_w, u_bias, v_bias, quB, qvB, kB, vtB, pB);
    attn_mfma<<<dim3(512), 256, 0, stream>>>(quB, qvB, kB, vtB, pB, attnb);
    out_gemm<<<dim3(256), 256, 0, stream>>>(attnb, out_w, out_b, out);
}